// Round 1
// baseline (1909.766 us; speedup 1.0000x reference)
//
#include <hip/hip_runtime.h>

typedef _Float16 h8 __attribute__((ext_vector_type(8)));
typedef float f4 __attribute__((ext_vector_type(4)));

#define B_ 4096
#define T_ 64
#define I_ 8
#define H_ 128
#define G_ 512

// ---------------- prep: pack weights (gate-interleaved, fp16), cvt x, zero state ----
__global__ __launch_bounds__(256) void prep_kernel(
    const float* __restrict__ x,
    const float* __restrict__ Wih0, const float* __restrict__ Whh0,
    const float* __restrict__ bih0, const float* __restrict__ bhh0,
    const float* __restrict__ Wih1, const float* __restrict__ Whh1,
    const float* __restrict__ bih1, const float* __restrict__ bhh1,
    _Float16* __restrict__ Wc0, _Float16* __restrict__ Wc1,
    float* __restrict__ bc0, float* __restrict__ bc1,
    _Float16* __restrict__ xh,
    _Float16* __restrict__ h0b1, _Float16* __restrict__ h1b1,
    float* __restrict__ c0, float* __restrict__ c1)
{
    const int i = blockIdx.x * 256 + threadIdx.x;   // grid covers 2M
    if (i < B_ * T_ * I_) xh[i] = (_Float16)x[i];
    if (i < G_ * 192) {                 // Wcomb0: [512][192] = [Whh0(128) | Wih0(8) | 0(56)]
        int cc = i / 192, k = i - cc * 192;
        int u = cc >> 2, gi = cc & 3, gs = gi * H_ + u;
        float val = 0.f;
        if (k < 128) val = Whh0[gs * H_ + k];
        else if (k < 136) val = Wih0[gs * I_ + (k - 128)];
        Wc0[i] = (_Float16)val;
    }
    if (i < G_ * 256) {                 // Wcomb1: [512][256] = [Whh1(128) | Wih1(128)]
        int cc = i >> 8, k = i & 255;
        int u = cc >> 2, gi = cc & 3, gs = gi * H_ + u;
        float val = (k < 128) ? Whh1[gs * H_ + k] : Wih1[gs * H_ + (k - 128)];
        Wc1[i] = (_Float16)val;
    }
    if (i < G_) {
        int u = i >> 2, gi = i & 3, gs = gi * H_ + u;
        bc0[i] = bih0[gs] + bhh0[gs];
        bc1[i] = bih1[gs] + bhh1[gs];
    }
    if (i < B_ * H_) {
        h0b1[i] = (_Float16)0.f;
        h1b1[i] = (_Float16)0.f;
        c0[i] = 0.f;
        c1[i] = 0.f;
    }
}

// ---------------- fused step kernel: blocks [0,nL0) do layer0 step t,
// blocks [nL0,..) do layer1 step t-1 -----------------------------------------
__global__ __launch_bounds__(256) void lstm_step_kernel(
    const _Float16* __restrict__ Wc0, const _Float16* __restrict__ Wc1,
    const float* __restrict__ bc0, const float* __restrict__ bc1,
    const _Float16* __restrict__ xh,
    const _Float16* __restrict__ h0_rd, _Float16* __restrict__ h0_wr,
    const _Float16* __restrict__ h1_rd, _Float16* __restrict__ h1_wr,
    float* __restrict__ c0st, float* __restrict__ c1st,
    int t, int nL0)
{
    __shared__ _Float16 Asm[128][72];   // rows x k-chunk (+8 pad: 36dw stride -> ~2-way)
    __shared__ _Float16 Bsm[128][72];   // gate-cols x k-chunk

    const int tid = threadIdx.x;
    const bool isL1 = (int)blockIdx.x >= nL0;
    const int pb = (int)blockIdx.x - (isL1 ? nL0 : 0);
    const int rowbase = (pb >> 2) * 128;
    const int colbase = (pb & 3) * 128;

    const _Float16* Wc = isL1 ? Wc1 : Wc0;
    const float* bc   = isL1 ? bc1 : bc0;
    const _Float16* hrd = isL1 ? h1_rd : h0_rd;
    _Float16* hwr     = isL1 ? h1_wr : h0_wr;
    float* cst        = isL1 ? c1st : c0st;
    const int Ktot    = isL1 ? 256 : 192;
    const int nchunk  = isL1 ? 4 : 3;

    f4 acc[4][4];
    const f4 zero4 = {0.f, 0.f, 0.f, 0.f};
#pragma unroll
    for (int i = 0; i < 4; i++)
#pragma unroll
        for (int j = 0; j < 4; j++) acc[i][j] = zero4;

    const int lrow = tid & 127;
    const bool doB = tid >= 128;
    const int l  = tid & 63;
    const int wv = tid >> 6;
    const int wr = (wv >> 1) * 64;
    const int wc = (wv & 1) * 64;
    const int lr = l & 15;
    const int lk = (l >> 4) * 8;

    for (int kc = 0; kc < nchunk; kc++) {
        h8 v[8];
        if (!doB) {
            const int r = rowbase + lrow;
            if (kc < 2) {
                const h8* p = (const h8*)(hrd + r * H_ + kc * 64);
#pragma unroll
                for (int i = 0; i < 8; i++) v[i] = p[i];
            } else if (!isL1) {         // k 128..191 = x_t (8) + zeros
                h8 z;
#pragma unroll
                for (int k = 0; k < 8; k++) z[k] = (_Float16)0.f;
                v[0] = *(const h8*)(xh + r * (T_ * I_) + t * I_);
#pragma unroll
                for (int i = 1; i < 8; i++) v[i] = z;
            } else {                    // k 128..255 = h0 (layer1 input)
                const h8* p = (const h8*)(h0_rd + r * H_ + (kc - 2) * 64);
#pragma unroll
                for (int i = 0; i < 8; i++) v[i] = p[i];
            }
        } else {
            const int c = colbase + lrow;
            const h8* p = (const h8*)(Wc + c * Ktot + kc * 64);
#pragma unroll
            for (int i = 0; i < 8; i++) v[i] = p[i];
        }
        __syncthreads();                // prev chunk's reads done
        {
            h8* dst = doB ? (h8*)&Bsm[lrow][0] : (h8*)&Asm[lrow][0];
#pragma unroll
            for (int i = 0; i < 8; i++) dst[i] = v[i];
        }
        __syncthreads();                // chunk staged

#pragma unroll
        for (int ki = 0; ki < 2; ki++) {
            h8 a[4], b[4];
#pragma unroll
            for (int i = 0; i < 4; i++)
                a[i] = *(const h8*)&Asm[wr + i * 16 + lr][ki * 32 + lk];
#pragma unroll
            for (int j = 0; j < 4; j++)
                b[j] = *(const h8*)&Bsm[wc + j * 16 + lr][ki * 32 + lk];
#pragma unroll
            for (int i = 0; i < 4; i++)
#pragma unroll
                for (int j = 0; j < 4; j++)
                    acc[i][j] = __builtin_amdgcn_mfma_f32_16x16x32_f16(
                        a[i], b[j], acc[i][j], 0, 0, 0);
        }
    }

    // ---- epilogue: gather i,f,g,o (adjacent cols = adjacent lanes) via shfl_xor,
    // LSTM pointwise update, write c (f32) and h (fp16)
    const int sel1 = l & 1, sel2 = l & 2;
#pragma unroll
    for (int j = 0; j < 4; j++) {
        const int c = colbase + wc + j * 16 + lr;
        const float bias = bc[c];
        const int u = c >> 2;
#pragma unroll
        for (int i = 0; i < 4; i++) {
#pragma unroll
            for (int q = 0; q < 4; q++) {
                float vown = acc[i][j][q] + bias;
                float x1 = __shfl_xor(vown, 1);
                float p0 = sel1 ? x1 : vown;   // even col of pair
                float p1 = sel1 ? vown : x1;   // odd col of pair
                float q0 = __shfl_xor(p0, 2);
                float q1 = __shfl_xor(p1, 2);
                float vi = sel2 ? q0 : p0;     // gate i  (col 4u+0)
                float vf = sel2 ? q1 : p1;     // gate f  (col 4u+1)
                float vg = sel2 ? p0 : q0;     // gate g  (col 4u+2)
                float vo = sel2 ? p1 : q1;     // gate o  (col 4u+3)
                float ig = 1.f / (1.f + __expf(-vi));
                float fg = 1.f / (1.f + __expf(-vf));
                float eg = __expf(2.f * fabsf(vg));
                float gg = copysignf(1.f - 2.f / (eg + 1.f), vg);
                float og = 1.f / (1.f + __expf(-vo));
                int r = rowbase + wr + i * 16 + (l >> 4) * 4 + q;
                float cp = cst[r * H_ + u];
                float cn = fg * cp + ig * gg;
                float ec = __expf(2.f * fabsf(cn));
                float th = copysignf(1.f - 2.f / (ec + 1.f), cn);
                float hn = og * th;
                if ((l & 3) == 0) cst[r * H_ + u] = cn;
                if ((l & 3) == 1) hwr[r * H_ + u] = (_Float16)hn;
            }
        }
    }
}

// ---------------- head: relu(h) @ Wd1 -> relu -> @ Wd2; one wave per row ----
__global__ __launch_bounds__(256) void head_kernel(
    const _Float16* __restrict__ h1, const float* __restrict__ Wd1,
    const float* __restrict__ bd1, const float* __restrict__ Wd2,
    const float* __restrict__ bd2, float* __restrict__ out)
{
    const int gid = blockIdx.x * 256 + threadIdx.x;
    const int r = gid >> 6;
    const int l = gid & 63;
    if (r >= B_) return;
    float a0 = fmaxf((float)h1[r * H_ + 2 * l], 0.f);
    float a1 = fmaxf((float)h1[r * H_ + 2 * l + 1], 0.f);
    float p[5];
#pragma unroll
    for (int j = 0; j < 5; j++)
        p[j] = a0 * Wd1[j * H_ + 2 * l] + a1 * Wd1[j * H_ + 2 * l + 1];
#pragma unroll
    for (int j = 0; j < 5; j++)
#pragma unroll
        for (int m = 1; m < 64; m <<= 1) p[j] += __shfl_xor(p[j], m);
    if (l == 0) {
        float o = bd2[0];
#pragma unroll
        for (int j = 0; j < 5; j++) o += fmaxf(p[j] + bd1[j], 0.f) * Wd2[j];
        out[r] = o;
    }
}

extern "C" void kernel_launch(void* const* d_in, const int* in_sizes, int n_in,
                              void* d_out, int out_size, void* d_ws, size_t ws_size,
                              hipStream_t stream)
{
    const float* x    = (const float*)d_in[0];
    const float* Wih0 = (const float*)d_in[1];
    const float* Whh0 = (const float*)d_in[2];
    const float* bih0 = (const float*)d_in[3];
    const float* bhh0 = (const float*)d_in[4];
    const float* Wih1 = (const float*)d_in[5];
    const float* Whh1 = (const float*)d_in[6];
    const float* bih1 = (const float*)d_in[7];
    const float* bhh1 = (const float*)d_in[8];
    const float* Wd1  = (const float*)d_in[9];
    const float* bd1  = (const float*)d_in[10];
    const float* Wd2  = (const float*)d_in[11];
    const float* bd2  = (const float*)d_in[12];

    char* ws = (char*)d_ws;
    size_t off = 0;
    auto alloc = [&](size_t bytes) {
        void* p = ws + off;
        off = (off + bytes + 255) & ~(size_t)255;
        return p;
    };
    _Float16* Wc0  = (_Float16*)alloc(512 * 192 * 2);
    _Float16* Wc1  = (_Float16*)alloc(512 * 256 * 2);
    float*    bc0  = (float*)alloc(512 * 4);
    float*    bc1  = (float*)alloc(512 * 4);
    _Float16* xh   = (_Float16*)alloc((size_t)B_ * T_ * I_ * 2);
    _Float16* h0b0 = (_Float16*)alloc((size_t)B_ * H_ * 2);
    _Float16* h0b1 = (_Float16*)alloc((size_t)B_ * H_ * 2);
    _Float16* h1b0 = (_Float16*)alloc((size_t)B_ * H_ * 2);
    _Float16* h1b1 = (_Float16*)alloc((size_t)B_ * H_ * 2);
    float*    c0   = (float*)alloc((size_t)B_ * H_ * 4);
    float*    c1   = (float*)alloc((size_t)B_ * H_ * 4);

    _Float16* h0b[2] = {h0b0, h0b1};
    _Float16* h1b[2] = {h1b0, h1b1};

    prep_kernel<<<(B_ * T_ * I_) / 256, 256, 0, stream>>>(
        x, Wih0, Whh0, bih0, bhh0, Wih1, Whh1, bih1, bhh1,
        Wc0, Wc1, bc0, bc1, xh, h0b1, h1b1, c0, c1);

    for (int t = 0; t <= 64; t++) {
        int nL0 = (t < 64) ? 128 : 0;
        int nL1 = (t >= 1) ? 128 : 0;
        lstm_step_kernel<<<nL0 + nL1, 256, 0, stream>>>(
            Wc0, Wc1, bc0, bc1, xh,
            h0b[(t + 1) & 1], h0b[t & 1],      // h0 read / write (ping-pong)
            h1b[t & 1], h1b[(t + 1) & 1],      // h1 read / write (ping-pong)
            c0, c1, t, nL0);
    }

    head_kernel<<<(B_ * 64) / 256, 256, 0, stream>>>(
        h1b[1], Wd1, bd1, Wd2, bd2, (float*)d_out);
}

// Round 2
// 202.177 us; speedup vs baseline: 9.4460x; 9.4460x over previous
//
#include <hip/hip_runtime.h>

typedef _Float16 h8 __attribute__((ext_vector_type(8)));
typedef float f4 __attribute__((ext_vector_type(4)));

#define B_ 4096
#define T_ 64
#define I_ 8
#define H_ 128

// LDS layout (bytes). Total 147456 <= 163840 (gfx950 LDS/CU).
#define WC0_OFF 0            // [512 gates][128 k] fp16, XOR-swizzled   = 131072
#define H0_OFF  131072       // 2 x [16 batch][128 u] fp16, swizzled    = 8192
#define H1_OFF  139264       // 2 x [16][128]                           = 8192
#define LDS_TOTAL 147456

__device__ __forceinline__ float sigm_(float v) {
    return __builtin_amdgcn_rcpf(1.f + exp2f(-1.4426950408889634f * v));
}
__device__ __forceinline__ float tanh_(float v) {
    // tanh(x) = 1 - 2/(e^{2x}+1); inf-safe at both ends
    return 1.f - 2.f * __builtin_amdgcn_rcpf(exp2f(2.8853900817779268f * v) + 1.f);
}

// One block = 16 batch rows, full 2-layer LSTM + head. 8 waves: wave w owns
// gate-cols [w*64, w*64+64). gatesT = Wc (M=512 gates) x h (N=16 batch).
// Lane l: batch = l&15, G4 = l>>4; frag j: u = w*16 + j*4 + G4,
// acc[j][q] = gate q (i,f,g,o) of (batch, u)  -> shuffle-free epilogue.
__global__ __launch_bounds__(512, 2) void lstm_fused_kernel(
    const float* __restrict__ x,
    const float* __restrict__ Wih0, const float* __restrict__ Whh0,
    const float* __restrict__ bih0, const float* __restrict__ bhh0,
    const float* __restrict__ Wih1, const float* __restrict__ Whh1,
    const float* __restrict__ bih1, const float* __restrict__ bhh1,
    const float* __restrict__ Wd1, const float* __restrict__ bd1,
    const float* __restrict__ Wd2, const float* __restrict__ bd2,
    float* __restrict__ out)
{
    __shared__ __align__(16) unsigned char lds[LDS_TOTAL];
    const int tid = threadIdx.x;
    const int w   = tid >> 6;
    const int l   = tid & 63;
    const int c16 = l & 15;        // batch col (B-frag/D-col) & gate row-in-tile (A-frag)
    const int G4  = l >> 4;
    const int rowbase = blockIdx.x * 16;
    const int swzl = (l & 7) << 4; // XOR key: gate&7 == batch&7 == l&7 for all our accesses

    // ---- init: Wc0 (gate-interleaved, fp16, swizzled) -> LDS; one gate-row per thread
    {
        const int g  = tid;                      // packed gate index 4u+gi
        const int gs = (g & 3) * H_ + (g >> 2);  // original row (gate-major)
        const float* src = Whh0 + (size_t)gs * H_;
        const int swz = (g & 7) << 4;
        unsigned char* dst = lds + WC0_OFF + g * 256;
#pragma unroll
        for (int kb = 0; kb < 16; kb++) {
            float4 f0 = *(const float4*)(src + kb * 8);
            float4 f1 = *(const float4*)(src + kb * 8 + 4);
            h8 v;
            v[0]=(_Float16)f0.x; v[1]=(_Float16)f0.y; v[2]=(_Float16)f0.z; v[3]=(_Float16)f0.w;
            v[4]=(_Float16)f1.x; v[5]=(_Float16)f1.y; v[6]=(_Float16)f1.z; v[7]=(_Float16)f1.w;
            *(h8*)(dst + ((kb * 16) ^ swz)) = v;
        }
    }
    // zero the t=0 read buffers (index 1)
    {
        f4 z = {0.f, 0.f, 0.f, 0.f};
        if (tid < 256) *(f4*)(lds + H0_OFF + 4096 + tid * 16) = z;
        else           *(f4*)(lds + H1_OFF + 4096 + (tid - 256) * 16) = z;
    }

    // ---- init: Wc1 A-frags -> regs; x-weights(+L0 bias) frag; L1 bias
    h8 wc1[4][8];
    h8 ax[4];
    f4 b1[4];
#pragma unroll
    for (int j = 0; j < 4; j++) {
        const int gate = w * 64 + j * 16 + c16;
        const int gs = (gate & 3) * H_ + (gate >> 2);
#pragma unroll
        for (int ks = 0; ks < 8; ks++) {
            const int k0 = ks * 32 + G4 * 8;
            const float* src = (k0 < 128) ? (Whh1 + (size_t)gs * H_ + k0)
                                          : (Wih1 + (size_t)gs * H_ + (k0 - 128));
            float4 f0 = *(const float4*)src;
            float4 f1 = *(const float4*)(src + 4);
            h8 v;
            v[0]=(_Float16)f0.x; v[1]=(_Float16)f0.y; v[2]=(_Float16)f0.z; v[3]=(_Float16)f0.w;
            v[4]=(_Float16)f1.x; v[5]=(_Float16)f1.y; v[6]=(_Float16)f1.z; v[7]=(_Float16)f1.w;
            wc1[j][ks] = v;
        }
        h8 a;
#pragma unroll
        for (int e = 0; e < 8; e++) a[e] = (_Float16)0.f;
        if (G4 == 0) {                       // k=0..7 : Wih0 row
            float4 f0 = *(const float4*)(Wih0 + (size_t)gs * I_);
            float4 f1 = *(const float4*)(Wih0 + (size_t)gs * I_ + 4);
            a[0]=(_Float16)f0.x; a[1]=(_Float16)f0.y; a[2]=(_Float16)f0.z; a[3]=(_Float16)f0.w;
            a[4]=(_Float16)f1.x; a[5]=(_Float16)f1.y; a[6]=(_Float16)f1.z; a[7]=(_Float16)f1.w;
        } else if (G4 == 1) {                // k=8 : combined L0 bias (x1.0 in B)
            a[0] = (_Float16)(bih0[gs] + bhh0[gs]);
        }
        ax[j] = a;
        f4 bb;
#pragma unroll
        for (int q = 0; q < 4; q++) {
            const int gate2 = w * 64 + j * 16 + G4 * 4 + q;   // D-row gate of acc[j][q]
            const int gs2 = (gate2 & 3) * H_ + (gate2 >> 2);
            bb[q] = bih1[gs2] + bhh1[gs2];
        }
        b1[j] = bb;
    }

    const float* xrow = x + (size_t)(rowbase + c16) * T_ * I_;
    float4 xf0 = *(const float4*)(xrow);
    float4 xf1 = *(const float4*)(xrow + 4);

    float c0r[4] = {0.f, 0.f, 0.f, 0.f};
    float c1r[4] = {0.f, 0.f, 0.f, 0.f};

    __syncthreads();

    int cur = 0;
    for (int t = 0; t < T_; t++) {
        // B-frag for the x/bias K=32 chunk
        h8 bx;
#pragma unroll
        for (int e = 0; e < 8; e++) bx[e] = (_Float16)0.f;
        if (G4 == 0) {
            bx[0]=(_Float16)xf0.x; bx[1]=(_Float16)xf0.y; bx[2]=(_Float16)xf0.z; bx[3]=(_Float16)xf0.w;
            bx[4]=(_Float16)xf1.x; bx[5]=(_Float16)xf1.y; bx[6]=(_Float16)xf1.z; bx[7]=(_Float16)xf1.w;
        } else if (G4 == 1) {
            bx[0] = (_Float16)1.f;           // multiplies the bias slot of ax
        }
        if (t < T_ - 1) {                    // prefetch next x under this step's compute
            xf0 = *(const float4*)(xrow + (t + 1) * 8);
            xf1 = *(const float4*)(xrow + (t + 1) * 8 + 4);
        }

        // ---------------- layer 0 : gates0 = Wc0 @ h0_old  (+ x/bias chunk)
        f4 acc[4];
        {
            f4 z = {0.f, 0.f, 0.f, 0.f};
#pragma unroll
            for (int j = 0; j < 4; j++) acc[j] = z;
        }
        const unsigned char* h0rd = lds + H0_OFF + (cur ^ 1) * 4096;
#pragma unroll
        for (int ks = 0; ks < 4; ks++) {
            h8 b = *(const h8*)(h0rd + ((c16 * 256 + ks * 64 + G4 * 16) ^ swzl));
#pragma unroll
            for (int j = 0; j < 4; j++) {
                h8 a = *(const h8*)(lds + WC0_OFF + (w * 64 + j * 16 + c16) * 256
                                    + ((ks * 64 + G4 * 16) ^ swzl));
                acc[j] = __builtin_amdgcn_mfma_f32_16x16x32_f16(a, b, acc[j], 0, 0, 0);
            }
        }
#pragma unroll
        for (int j = 0; j < 4; j++)
            acc[j] = __builtin_amdgcn_mfma_f32_16x16x32_f16(ax[j], bx, acc[j], 0, 0, 0);

        unsigned char* h0wr = lds + H0_OFF + cur * 4096;
#pragma unroll
        for (int j = 0; j < 4; j++) {
            const float vi = sigm_(acc[j][0]);
            const float vf = sigm_(acc[j][1]);
            const float vg = tanh_(acc[j][2]);
            const float vo = sigm_(acc[j][3]);
            const float cn = vf * c0r[j] + vi * vg;
            c0r[j] = cn;
            const float hn = vo * tanh_(cn);
            const int u = w * 16 + j * 4 + G4;
            *(_Float16*)(h0wr + ((c16 * 256 + u * 2) ^ swzl)) = (_Float16)hn;
        }

        __syncthreads();   // h0_new visible to all waves; sole barrier per step

        // ---------------- layer 1 : gates1 = Wc1 @ [h1_old | h0_new] + b1
        const unsigned char* h1rd = lds + H1_OFF + (cur ^ 1) * 4096;
        const unsigned char* h0n  = lds + H0_OFF + cur * 4096;
#pragma unroll
        for (int j = 0; j < 4; j++) acc[j] = b1[j];
#pragma unroll
        for (int ks = 0; ks < 4; ks++) {
            h8 b = *(const h8*)(h1rd + ((c16 * 256 + ks * 64 + G4 * 16) ^ swzl));
#pragma unroll
            for (int j = 0; j < 4; j++)
                acc[j] = __builtin_amdgcn_mfma_f32_16x16x32_f16(wc1[j][ks], b, acc[j], 0, 0, 0);
        }
#pragma unroll
        for (int ks = 0; ks < 4; ks++) {
            h8 b = *(const h8*)(h0n + ((c16 * 256 + ks * 64 + G4 * 16) ^ swzl));
#pragma unroll
            for (int j = 0; j < 4; j++)
                acc[j] = __builtin_amdgcn_mfma_f32_16x16x32_f16(wc1[j][ks + 4], b, acc[j], 0, 0, 0);
        }
        unsigned char* h1wr = lds + H1_OFF + cur * 4096;
#pragma unroll
        for (int j = 0; j < 4; j++) {
            const float vi = sigm_(acc[j][0]);
            const float vf = sigm_(acc[j][1]);
            const float vg = tanh_(acc[j][2]);
            const float vo = sigm_(acc[j][3]);
            const float cn = vf * c1r[j] + vi * vg;
            c1r[j] = cn;
            const float hn = vo * tanh_(cn);
            const int u = w * 16 + j * 4 + G4;
            *(_Float16*)(h1wr + ((c16 * 256 + u * 2) ^ swzl)) = (_Float16)hn;
        }
        cur ^= 1;
    }

    __syncthreads();       // final h1 (buffer 1) ready for the head

    // ---------------- head: out = relu(relu(h1) @ Wd1^T + bd1) @ Wd2^T + bd2
    if (tid < 128) {
        const int r = tid >> 3, part = tid & 7;
        const unsigned char* h1f = lds + H1_OFF + 4096;   // t=63 wrote buffer 1
        const int rswz = (r & 7) << 4;
        float s0 = 0.f, s1 = 0.f, s2 = 0.f, s3 = 0.f, s4 = 0.f;
#pragma unroll
        for (int kk = 0; kk < 16; kk++) {
            const int k = part * 16 + kk;
            float a = (float)*(const _Float16*)(h1f + ((r * 256 + k * 2) ^ rswz));
            a = fmaxf(a, 0.f);
            s0 += a * Wd1[0 * H_ + k];
            s1 += a * Wd1[1 * H_ + k];
            s2 += a * Wd1[2 * H_ + k];
            s3 += a * Wd1[3 * H_ + k];
            s4 += a * Wd1[4 * H_ + k];
        }
#pragma unroll
        for (int m = 1; m < 8; m <<= 1) {
            s0 += __shfl_xor(s0, m);
            s1 += __shfl_xor(s1, m);
            s2 += __shfl_xor(s2, m);
            s3 += __shfl_xor(s3, m);
            s4 += __shfl_xor(s4, m);
        }
        if (part == 0) {
            float o = bd2[0];
            o += fmaxf(s0 + bd1[0], 0.f) * Wd2[0];
            o += fmaxf(s1 + bd1[1], 0.f) * Wd2[1];
            o += fmaxf(s2 + bd1[2], 0.f) * Wd2[2];
            o += fmaxf(s3 + bd1[3], 0.f) * Wd2[3];
            o += fmaxf(s4 + bd1[4], 0.f) * Wd2[4];
            out[rowbase + r] = o;
        }
    }
}

extern "C" void kernel_launch(void* const* d_in, const int* in_sizes, int n_in,
                              void* d_out, int out_size, void* d_ws, size_t ws_size,
                              hipStream_t stream)
{
    const float* x    = (const float*)d_in[0];
    const float* Wih0 = (const float*)d_in[1];
    const float* Whh0 = (const float*)d_in[2];
    const float* bih0 = (const float*)d_in[3];
    const float* bhh0 = (const float*)d_in[4];
    const float* Wih1 = (const float*)d_in[5];
    const float* Whh1 = (const float*)d_in[6];
    const float* bih1 = (const float*)d_in[7];
    const float* bhh1 = (const float*)d_in[8];
    const float* Wd1  = (const float*)d_in[9];
    const float* bd1  = (const float*)d_in[10];
    const float* Wd2  = (const float*)d_in[11];
    const float* bd2  = (const float*)d_in[12];

    lstm_fused_kernel<<<B_ / 16, 512, 0, stream>>>(
        x, Wih0, Whh0, bih0, bhh0, Wih1, Whh1, bih1, bhh1,
        Wd1, bd1, Wd2, bd2, (float*)d_out);
}

// Round 3
// 202.004 us; speedup vs baseline: 9.4541x; 1.0009x over previous
//
#include <hip/hip_runtime.h>

typedef _Float16 h8 __attribute__((ext_vector_type(8)));
typedef _Float16 h4 __attribute__((ext_vector_type(4)));
typedef float f4 __attribute__((ext_vector_type(4)));

#define B_ 4096
#define T_ 64
#define I_ 8
#define H_ 128

// LDS layout (bytes). Total 147456 <= 163840.
#define WC0_OFF 0            // [512 packed-gates][128 k] fp16, XOR-swizzled = 131072
#define H0_OFF  131072       // 2 x [16 batch][128 u] fp16, swizzled        = 8192
#define H1_OFF  139264       // 2 x [16][128]                               = 8192
#define LDS_TOTAL 147456

#define LOG2E    1.4426950408889634f
#define TWOLOG2E 2.8853900817779268f

// gates arrive pre-scaled by log2e (i,f,o) / 2*log2e (g)
__device__ __forceinline__ float sigm2_(float v) {
    return __builtin_amdgcn_rcpf(1.f + exp2f(-v));
}
__device__ __forceinline__ float tanh2_(float v) {
    return 1.f - 2.f * __builtin_amdgcn_rcpf(exp2f(v) + 1.f);
}
__device__ __forceinline__ float tanhn_(float v) {   // natural units (for c)
    return 1.f - 2.f * __builtin_amdgcn_rcpf(exp2f(TWOLOG2E * v) + 1.f);
}

// Packed gate order: packed row p = w*64 + j*16 + r, r = G4*4 + q.
// p maps to (u = w*16 + G4*4 + j, gate q) -> original row gs = q*128 + u.
// => thread (w, G4, c16) owns u = w*16+G4*4+{j=0..3} (contiguous) for batch c16:
//    epilogue writes ONE ds_write_b64 per layer.
__global__ __launch_bounds__(512, 2) void lstm_fused_kernel(
    const float* __restrict__ x,
    const float* __restrict__ Wih0, const float* __restrict__ Whh0,
    const float* __restrict__ bih0, const float* __restrict__ bhh0,
    const float* __restrict__ Wih1, const float* __restrict__ Whh1,
    const float* __restrict__ bih1, const float* __restrict__ bhh1,
    const float* __restrict__ Wd1, const float* __restrict__ bd1,
    const float* __restrict__ Wd2, const float* __restrict__ bd2,
    float* __restrict__ out)
{
    __shared__ __align__(16) unsigned char lds[LDS_TOTAL];
    const int tid = threadIdx.x;
    const int w   = tid >> 6;
    const int l   = tid & 63;
    const int c16 = l & 15;
    const int G4  = l >> 4;
    const int rowbase = blockIdx.x * 16;
    const int swzl = (l & 7) << 4;

    // ---- init: Wc0 (packed order, prescaled, fp16, swizzled) -> LDS
    {
        const int p  = tid;
        const int q  = p & 3;
        const int gs = q * H_ + (p >> 6) * 16 + ((p >> 2) & 3) * 4 + ((p >> 4) & 3);
        const float sc = (q == 2) ? TWOLOG2E : LOG2E;
        const float* src = Whh0 + (size_t)gs * H_;
        const int swz = (p & 7) << 4;
        unsigned char* dst = lds + WC0_OFF + p * 256;
#pragma unroll
        for (int kb = 0; kb < 16; kb++) {
            float4 f0 = *(const float4*)(src + kb * 8);
            float4 f1 = *(const float4*)(src + kb * 8 + 4);
            h8 v;
            v[0]=(_Float16)(f0.x*sc); v[1]=(_Float16)(f0.y*sc);
            v[2]=(_Float16)(f0.z*sc); v[3]=(_Float16)(f0.w*sc);
            v[4]=(_Float16)(f1.x*sc); v[5]=(_Float16)(f1.y*sc);
            v[6]=(_Float16)(f1.z*sc); v[7]=(_Float16)(f1.w*sc);
            *(h8*)(dst + ((kb * 16) ^ swz)) = v;
        }
    }
    // zero the t=0 read buffers (index 1)
    {
        f4 z = {0.f, 0.f, 0.f, 0.f};
        if (tid < 256) *(f4*)(lds + H0_OFF + 4096 + tid * 16) = z;
        else           *(f4*)(lds + H1_OFF + 4096 + (tid - 256) * 16) = z;
    }

    // ---- init: Wc1 A-frags + x-weight/bias frag (K=16) + L1 bias, all prescaled
    h8 wc1[4][8];
    h4 ax16[4];
    f4 b1[4];
    {
        const int rq = c16 & 3;
        const float sc1 = (rq == 2) ? TWOLOG2E : LOG2E;
#pragma unroll
        for (int j = 0; j < 4; j++) {
            const int gs = rq * H_ + w * 16 + (c16 >> 2) * 4 + j;
#pragma unroll
            for (int ks = 0; ks < 8; ks++) {
                const int k0 = ks * 32 + G4 * 8;
                const float* src = (k0 < 128) ? (Whh1 + (size_t)gs * H_ + k0)
                                              : (Wih1 + (size_t)gs * H_ + (k0 - 128));
                float4 f0 = *(const float4*)src;
                float4 f1 = *(const float4*)(src + 4);
                h8 v;
                v[0]=(_Float16)(f0.x*sc1); v[1]=(_Float16)(f0.y*sc1);
                v[2]=(_Float16)(f0.z*sc1); v[3]=(_Float16)(f0.w*sc1);
                v[4]=(_Float16)(f1.x*sc1); v[5]=(_Float16)(f1.y*sc1);
                v[6]=(_Float16)(f1.z*sc1); v[7]=(_Float16)(f1.w*sc1);
                wc1[j][ks] = v;
            }
            h4 a;
#pragma unroll
            for (int e = 0; e < 4; e++) {
                const int k = G4 * 4 + e;
                float val = 0.f;
                if (k < 8)       val = Wih0[(size_t)gs * I_ + k] * sc1;
                else if (k == 8) val = (bih0[gs] + bhh0[gs]) * sc1;
                a[e] = (_Float16)val;
            }
            ax16[j] = a;
            f4 bb;
#pragma unroll
            for (int q2 = 0; q2 < 4; q2++) {
                const int gs2 = q2 * H_ + w * 16 + G4 * 4 + j;
                bb[q2] = (bih1[gs2] + bhh1[gs2]) * ((q2 == 2) ? TWOLOG2E : LOG2E);
            }
            b1[j] = bb;
        }
    }

    const float* xrow = x + (size_t)(rowbase + c16) * T_ * I_;
    float4 xf0 = *(const float4*)(xrow);
    float4 xf1 = *(const float4*)(xrow + 4);

    float c0r[4] = {0.f, 0.f, 0.f, 0.f};
    float c1r[4] = {0.f, 0.f, 0.f, 0.f};

    __syncthreads();

    int cur = 0;
    for (int t = 0; t < T_; t++) {
        // B-frag (K=16) for the x/bias chunk: k<8 = x_t, k=8 -> 1.0
        h4 bx;
        bx[0] = (_Float16)0.f; bx[1] = (_Float16)0.f;
        bx[2] = (_Float16)0.f; bx[3] = (_Float16)0.f;
        if (G4 == 0) {
            bx[0]=(_Float16)xf0.x; bx[1]=(_Float16)xf0.y;
            bx[2]=(_Float16)xf0.z; bx[3]=(_Float16)xf0.w;
        } else if (G4 == 1) {
            bx[0]=(_Float16)xf1.x; bx[1]=(_Float16)xf1.y;
            bx[2]=(_Float16)xf1.z; bx[3]=(_Float16)xf1.w;
        } else if (G4 == 2) {
            bx[0] = (_Float16)1.f;
        }
        if (t < T_ - 1) {
            xf0 = *(const float4*)(xrow + (t + 1) * 8);
            xf1 = *(const float4*)(xrow + (t + 1) * 8 + 4);
        }

        // ---------------- layer 0
        f4 acc[4];
        {
            f4 z = {0.f, 0.f, 0.f, 0.f};
#pragma unroll
            for (int j = 0; j < 4; j++) acc[j] = z;
        }
        const unsigned char* h0rd = lds + H0_OFF + (cur ^ 1) * 4096;
#pragma unroll
        for (int ks = 0; ks < 4; ks++) {
            h8 b = *(const h8*)(h0rd + ((c16 * 256 + ks * 64 + G4 * 16) ^ swzl));
#pragma unroll
            for (int j = 0; j < 4; j++) {
                h8 a = *(const h8*)(lds + WC0_OFF + (w * 64 + j * 16 + c16) * 256
                                    + ((ks * 64 + G4 * 16) ^ swzl));
                acc[j] = __builtin_amdgcn_mfma_f32_16x16x32_f16(a, b, acc[j], 0, 0, 0);
            }
        }
#pragma unroll
        for (int j = 0; j < 4; j++)
            acc[j] = __builtin_amdgcn_mfma_f32_16x16x16f16(ax16[j], bx, acc[j], 0, 0, 0);

        unsigned char* h0wr = lds + H0_OFF + cur * 4096;
        {
            h4 hv;
#pragma unroll
            for (int j = 0; j < 4; j++) {
                const float vi = sigm2_(acc[j][0]);
                const float vf = sigm2_(acc[j][1]);
                const float vg = tanh2_(acc[j][2]);
                const float vo = sigm2_(acc[j][3]);
                const float cn = vf * c0r[j] + vi * vg;
                c0r[j] = cn;
                hv[j] = (_Float16)(vo * tanhn_(cn));
            }
            *(h4*)(h0wr + ((c16 * 256 + w * 32 + G4 * 8) ^ swzl)) = hv;
        }

        __syncthreads();   // sole barrier per step

        // ---------------- layer 1
        const unsigned char* h1rd = lds + H1_OFF + (cur ^ 1) * 4096;
        const unsigned char* h0n  = lds + H0_OFF + cur * 4096;
#pragma unroll
        for (int j = 0; j < 4; j++) acc[j] = b1[j];
#pragma unroll
        for (int ks = 0; ks < 4; ks++) {
            h8 b = *(const h8*)(h1rd + ((c16 * 256 + ks * 64 + G4 * 16) ^ swzl));
#pragma unroll
            for (int j = 0; j < 4; j++)
                acc[j] = __builtin_amdgcn_mfma_f32_16x16x32_f16(wc1[j][ks], b, acc[j], 0, 0, 0);
        }
#pragma unroll
        for (int ks = 0; ks < 4; ks++) {
            h8 b = *(const h8*)(h0n + ((c16 * 256 + ks * 64 + G4 * 16) ^ swzl));
#pragma unroll
            for (int j = 0; j < 4; j++)
                acc[j] = __builtin_amdgcn_mfma_f32_16x16x32_f16(wc1[j][ks + 4], b, acc[j], 0, 0, 0);
        }
        unsigned char* h1wr = lds + H1_OFF + cur * 4096;
        {
            h4 hv;
#pragma unroll
            for (int j = 0; j < 4; j++) {
                const float vi = sigm2_(acc[j][0]);
                const float vf = sigm2_(acc[j][1]);
                const float vg = tanh2_(acc[j][2]);
                const float vo = sigm2_(acc[j][3]);
                const float cn = vf * c1r[j] + vi * vg;
                c1r[j] = cn;
                hv[j] = (_Float16)(vo * tanhn_(cn));
            }
            *(h4*)(h1wr + ((c16 * 256 + w * 32 + G4 * 8) ^ swzl)) = hv;
        }
        cur ^= 1;
    }

    __syncthreads();

    // ---------------- head
    if (tid < 128) {
        const int r = tid >> 3, part = tid & 7;
        const unsigned char* h1f = lds + H1_OFF + 4096;   // t=63 wrote buffer 1
        const int rswz = (r & 7) << 4;
        float s0 = 0.f, s1 = 0.f, s2 = 0.f, s3 = 0.f, s4 = 0.f;
#pragma unroll
        for (int kk = 0; kk < 16; kk++) {
            const int k = part * 16 + kk;
            float a = (float)*(const _Float16*)(h1f + ((r * 256 + k * 2) ^ rswz));
            a = fmaxf(a, 0.f);
            s0 += a * Wd1[0 * H_ + k];
            s1 += a * Wd1[1 * H_ + k];
            s2 += a * Wd1[2 * H_ + k];
            s3 += a * Wd1[3 * H_ + k];
            s4 += a * Wd1[4 * H_ + k];
        }
#pragma unroll
        for (int m = 1; m < 8; m <<= 1) {
            s0 += __shfl_xor(s0, m);
            s1 += __shfl_xor(s1, m);
            s2 += __shfl_xor(s2, m);
            s3 += __shfl_xor(s3, m);
            s4 += __shfl_xor(s4, m);
        }
        if (part == 0) {
            float o = bd2[0];
            o += fmaxf(s0 + bd1[0], 0.f) * Wd2[0];
            o += fmaxf(s1 + bd1[1], 0.f) * Wd2[1];
            o += fmaxf(s2 + bd1[2], 0.f) * Wd2[2];
            o += fmaxf(s3 + bd1[3], 0.f) * Wd2[3];
            o += fmaxf(s4 + bd1[4], 0.f) * Wd2[4];
            out[rowbase + r] = o;
        }
    }
}

extern "C" void kernel_launch(void* const* d_in, const int* in_sizes, int n_in,
                              void* d_out, int out_size, void* d_ws, size_t ws_size,
                              hipStream_t stream)
{
    const float* x    = (const float*)d_in[0];
    const float* Wih0 = (const float*)d_in[1];
    const float* Whh0 = (const float*)d_in[2];
    const float* bih0 = (const float*)d_in[3];
    const float* bhh0 = (const float*)d_in[4];
    const float* Wih1 = (const float*)d_in[5];
    const float* Whh1 = (const float*)d_in[6];
    const float* bih1 = (const float*)d_in[7];
    const float* bhh1 = (const float*)d_in[8];
    const float* Wd1  = (const float*)d_in[9];
    const float* bd1  = (const float*)d_in[10];
    const float* Wd2  = (const float*)d_in[11];
    const float* bd2  = (const float*)d_in[12];

    lstm_fused_kernel<<<B_ / 16, 512, 0, stream>>>(
        x, Wih0, Whh0, bih0, bhh0, Wih1, Whh1, bih1, bhh1,
        Wd1, bd1, Wd2, bd2, (float*)d_out);
}